// Round 17
// baseline (215.060 us; speedup 1.0000x reference)
//
#include <hip/hip_runtime.h>
#include <hip/hip_bf16.h>
#include <hip/hip_fp16.h>

#define NNODES 100000
#define NEDGES 2500000
#define CIN 32
#define CHID 16
#define COUT 64
#define NGRAPH 64

#define NPB 256                 // nodes per binsort bucket
#define NBUCKET 391             // ceil(100000/256)
#define BCAP 7424               // per-bucket raw capacity (mean 6394, ~13 sigma)
#define TILE 8192               // edges per binsort block (R14-proven)
#define NTB 306                 // ceil(2.5M/8192)
#define TBL 196                 // ceil(100000/512) transform blocks
#define NHALF 782               // 2 half-buckets (128 nodes) per bucket
#define BSTRIDE_H 4864          // per-half padded csr stride
#define AGG_BLOCKS 3125         // 100000 / 32 nodes per block (8 lanes/node)
#define SEGCAP 2048             // agg2 LDS csr segment cap (32 nodes, ~912 avg, 40 sigma)

// ---------------- workspace layout (4-byte units) ----------------------------
// gcnt  [0, 512)               int, zeroed (391 used)
// ginv  [1024, 1088)           f32
// offs  [1088, 101088)         int (padded csr start per node)
// deg   [101120, 201120)       int (true in-degree)
// csr   [201216, 4004864)      int, per-half stride BSTRIDE_H, pad = NNODES
// ebuf  [4004864, 6907648)     int packed (src<<8)|dst_local
// xlh   [6907648, 7707712)     f16 (N+1)*16 (row N = zeros)
// xr    [7707712, 9307712)     f32 N*16
// hh    [9307712, 10107720)    f16 (N+1)*16 (row N = zeros)  => 40.4 MB
#define OFF_GCNT  0
#define OFF_GINV  1024
#define OFF_OFFS  1088
#define OFF_DEG   101120
#define OFF_CSR   201216
#define OFF_EBUF  4004864
#define OFF_XLH   6907648
#define OFF_XR    7707712
#define OFF_HH    9307712

__device__ inline float4 unpack_h4(uint2 v) {
    __half2 p0 = *reinterpret_cast<__half2*>(&v.x);
    __half2 p1 = *reinterpret_cast<__half2*>(&v.y);
    float2 f0 = __half22float2(p0), f1 = __half22float2(p1);
    return make_float4(f0.x, f0.y, f1.x, f1.y);
}

__device__ inline uint2 pack_h4(float a, float b, float c, float d) {
    __half2 h0 = __floats2half2_rn(a, b);
    __half2 h1 = __floats2half2_rn(c, d);
    uint2 r;
    r.x = *reinterpret_cast<unsigned int*>(&h0);
    r.y = *reinterpret_cast<unsigned int*>(&h1);
    return r;
}

__device__ inline int lower_bound_i(const int* __restrict__ b, int n, int key) {
    int lo = 0, hi = n;
    while (lo < hi) {
        int m = (lo + hi) >> 1;
        if (b[m] < key) lo = m + 1; else hi = m;
    }
    return lo;
}

// FUSED stage 1: blocks [0,306) binsort | [306,502) transform1 | 502 graph_inv.
__global__ __launch_bounds__(512) void build_stage1(const int* __restrict__ src,
                                                    const int* __restrict__ dst,
                                                    int* __restrict__ gcnt,
                                                    int* __restrict__ ebuf,
                                                    const float* __restrict__ x,
                                                    const float* __restrict__ w1l,
                                                    const float* __restrict__ b1,
                                                    const float* __restrict__ w1r,
                                                    __half2* __restrict__ xlh2,
                                                    float* __restrict__ xr,
                                                    const int* __restrict__ batch,
                                                    float* __restrict__ ginv) {
    __shared__ int hist[NBUCKET];
    __shared__ int binstart[NBUCKET];
    __shared__ int cursor[NBUCKET];
    __shared__ int gbase[NBUCKET];
    __shared__ int tmp[512];
    __shared__ int sbuf[TILE];
    __shared__ float wl[CHID * CIN];
    __shared__ float wr[CHID * CIN];
    __shared__ float bs[CHID];

    int tid = threadIdx.x;

    if (blockIdx.x < NTB) {
        // ================= binsort =================
        int base = blockIdx.x * TILE;
        int cnt = min(NEDGES - base, TILE);
        for (int i = tid; i < NBUCKET; i += 512) hist[i] = 0;
        __syncthreads();
        int v[16], k[16];
#pragma unroll
        for (int j = 0; j < 16; j++) {
            int i = tid + j * 512;
            if (i < cnt) {
                int d = dst[base + i], s = src[base + i];
                k[j] = d >> 8;
                v[j] = (s << 8) | (d & 255);
                atomicAdd(&hist[k[j]], 1);
            }
        }
        __syncthreads();
        int hv = (tid < NBUCKET) ? hist[tid] : 0;
        tmp[tid] = hv;
        __syncthreads();
#pragma unroll
        for (int dd = 1; dd < 512; dd <<= 1) {
            int u = (tid >= dd) ? tmp[tid - dd] : 0;
            __syncthreads();
            tmp[tid] += u;
            __syncthreads();
        }
        if (tid < NBUCKET) {
            int excl = tmp[tid] - hv;
            binstart[tid] = excl;
            cursor[tid] = excl;
            gbase[tid] = (hv > 0) ? atomicAdd(&gcnt[tid], hv) : 0;
        }
        __syncthreads();
#pragma unroll
        for (int j = 0; j < 16; j++) {
            int i = tid + j * 512;
            if (i < cnt) {
                int p = atomicAdd(&cursor[k[j]], 1);
                sbuf[p] = v[j];
            }
        }
        __syncthreads();
        int wave = tid >> 6, lane = tid & 63;
        for (int b = wave; b < NBUCKET; b += 8) {
            int c2 = hist[b];
            if (c2 == 0) continue;
            int g = gbase[b];
            int gs = min(g, BCAP);
            int ncopy = min(g + c2, BCAP) - gs;    // overflow-guarded
            int ls = binstart[b];
            int* dp = ebuf + (size_t)b * BCAP + gs;
            for (int i = lane; i < ncopy; i += 64) dp[i] = sbuf[ls + i];
        }
    } else if (blockIdx.x < NTB + TBL) {
        // ================= transform1 =================
        int bid = blockIdx.x - NTB;
        for (int i = tid; i < CHID * CIN; i += 512) { wl[i] = w1l[i]; wr[i] = w1r[i]; }
        if (tid < CHID) bs[tid] = b1[tid];
        if (bid == 0 && tid < 8)
            xlh2[(size_t)NNODES * 8 + tid] = __floats2half2_rn(0.f, 0.f);  // pad row
        __syncthreads();
        int n = bid * 512 + tid;
        if (n >= NNODES) return;
        float xv[CIN];
        const float4* x4 = (const float4*)(x + (size_t)n * CIN);
#pragma unroll
        for (int q = 0; q < CIN / 4; q++) {
            float4 v = x4[q];
            xv[4*q] = v.x; xv[4*q+1] = v.y; xv[4*q+2] = v.z; xv[4*q+3] = v.w;
        }
        float oL[CHID];
#pragma unroll
        for (int o = 0; o < CHID; o++) {
            float aL = 0.f, aR = bs[o];
#pragma unroll
            for (int i = 0; i < CIN; i++) {
                aL = fmaf(wl[o * CIN + i], xv[i], aL);
                aR = fmaf(wr[o * CIN + i], xv[i], aR);
            }
            oL[o] = aL;
            xr[(size_t)n * CHID + o] = aR;
        }
#pragma unroll
        for (int q = 0; q < CHID / 2; q++)
            xlh2[(size_t)n * 8 + q] = __floats2half2_rn(oL[2*q], oL[2*q+1]);
    } else {
        // ================= graph_inv =================
        if (tid < NGRAPH) {
            int s = lower_bound_i(batch, NNODES, tid);
            int e = lower_bound_i(batch, NNODES, tid + 1);
            ginv[tid] = 1.0f / (float)max(e - s, 1);
        }
    }
}

// FUSED bucket_build + layer-1 aggregation (R14-proven); int4 lcsr gather reads.
__global__ __launch_bounds__(1024) void build_agg1(const int* __restrict__ gcnt,
                                                   const int* __restrict__ ebuf,
                                                   int* __restrict__ csr,
                                                   int* __restrict__ offs,
                                                   int* __restrict__ deg,
                                                   const uint2* __restrict__ xlh4,
                                                   const float* __restrict__ xr,
                                                   uint2* __restrict__ hh4) {
    __shared__ int lcsr[BSTRIDE_H];       // 19.5 KB padded LDS csr
    __shared__ int hist[128];
    __shared__ int cur[128];
    __shared__ int offs_s[128];
    __shared__ int deg_s[128];
    __shared__ int tmp[128];
    int b = blockIdx.x, tid = threadIdx.x;
    int b256 = b >> 1, half = b & 1;
    int nodes0 = (b256 << 8) + (half << 7);
    int nloc = min(128, NNODES - nodes0);
    int cnt = min(gcnt[b256], BCAP);
    int hbit = half << 7;
    if (tid < 128) hist[tid] = 0;
    if (b == 0 && tid < 4) {
        uint2 z; z.x = 0u; z.y = 0u;
        hh4[(size_t)NNODES * 4 + tid] = z;     // zero hh pad row for agg2
    }
    __syncthreads();
    const int* run = ebuf + (size_t)b256 * BCAP;
    for (int i = tid; i < cnt; i += 1024) {
        int dl = run[i] & 255;
        if ((dl & 128) == hbit) atomicAdd(&hist[dl & 127], 1);
    }
    __syncthreads();
    if (tid < 128) tmp[tid] = (hist[tid] + 7) & ~7;
    __syncthreads();
#pragma unroll
    for (int s = 1; s < 128; s <<= 1) {
        int u = (tid < 128 && tid >= s) ? tmp[tid - s] : 0;
        __syncthreads();
        if (tid < 128) tmp[tid] += u;
        __syncthreads();
    }
    if (tid < 128) {
        int d = hist[tid];
        int pc = (d + 7) & ~7;
        int excl = tmp[tid] - pc;
        cur[tid] = excl;
        offs_s[tid] = excl;
        deg_s[tid] = d;
        if (tid < nloc) {
            offs[nodes0 + tid] = b * BSTRIDE_H + excl;
            deg[nodes0 + tid] = d;
        }
    }
    __syncthreads();
    int* bcsr = csr + (size_t)b * BSTRIDE_H;
    for (int i = tid; i < cnt; i += 1024) {
        int v = run[i];
        int dl = v & 255;
        if ((dl & 128) == hbit) {
            int p = atomicAdd(&cur[dl & 127], 1);
            int sid = v >> 8;
            lcsr[p] = sid;
            bcsr[p] = sid;                 // mirror for agg2
        }
    }
    __syncthreads();
    if (tid < 128) {
        int fs = cur[tid];
        int fe = offs_s[tid] + ((deg_s[tid] + 7) & ~7);
        for (int k2 = fs; k2 < fe; k2++) { lcsr[k2] = NNODES; bcsr[k2] = NNODES; }
    }
    __syncthreads();

    // ---- aggregation: 128 slots x 8 lanes (2 half-lists x 4 channel-lanes) --
    int slot = tid >> 3;
    int sub  = (tid >> 2) & 1;
    int c4   = tid & 3;
    int s0 = offs_s[slot];
    int d  = deg_s[slot];
    int tot = (d + 7) >> 3;
    int itA = (tot + 1) >> 1;
    int myIters = sub ? (tot - itA) : itA;
    const int4* cp4 = (const int4*)(lcsr + s0 + (sub ? (itA << 3) : 0));
    float4 a0 = {0,0,0,0}, a1 = {0,0,0,0}, a2 = {0,0,0,0}, a3 = {0,0,0,0};
    float4 a4 = {0,0,0,0}, a5 = {0,0,0,0}, a6 = {0,0,0,0}, a7 = {0,0,0,0};
    for (int it = 0; it < myIters; it++, cp4 += 2) {
        int4 w0 = cp4[0], w1 = cp4[1];
        a0 += unpack_h4(xlh4[(size_t)w0.x * 4 + c4]);
        a1 += unpack_h4(xlh4[(size_t)w0.y * 4 + c4]);
        a2 += unpack_h4(xlh4[(size_t)w0.z * 4 + c4]);
        a3 += unpack_h4(xlh4[(size_t)w0.w * 4 + c4]);
        a4 += unpack_h4(xlh4[(size_t)w1.x * 4 + c4]);
        a5 += unpack_h4(xlh4[(size_t)w1.y * 4 + c4]);
        a6 += unpack_h4(xlh4[(size_t)w1.z * 4 + c4]);
        a7 += unpack_h4(xlh4[(size_t)w1.w * 4 + c4]);
    }
    float4 s = ((a0 + a1) + (a2 + a3)) + ((a4 + a5) + (a6 + a7));
    s.x += __shfl_xor(s.x, 4);
    s.y += __shfl_xor(s.y, 4);
    s.z += __shfl_xor(s.z, 4);
    s.w += __shfl_xor(s.w, 4);
    if (sub == 0 && slot < nloc) {
        int node = nodes0 + slot;
        float inv = 1.0f / (float)max(d, 1);
        float4 r = *(const float4*)(xr + (size_t)node * CHID + c4 * 4);
        float h0 = fmaxf(fmaf(s.x, inv, r.x), 0.f);
        float h1 = fmaxf(fmaf(s.y, inv, r.y), 0.f);
        float h2 = fmaxf(fmaf(s.z, inv, r.z), 0.f);
        float h3 = fmaxf(fmaf(s.w, inv, r.w), 0.f);
        hh4[(size_t)node * 4 + c4] = pack_h4(h0, h1, h2, h3);
    }
}

// layer-2 aggregate + output transform + fused graph pooling.
// R16 shape (3125x256) + NEW: the block's 32-node csr segment (contiguous,
// <=SEGCAP ints) is bulk-staged into LDS with int4 loads, then the gather
// reads indices from LDS -> csr-load leg leaves the dependent chain while
// keeping the small-block latency hiding that R15's reshape destroyed.
__global__ __launch_bounds__(256) void agg2_pool(const int* __restrict__ offs,
                                                 const int* __restrict__ deg,
                                                 const int* __restrict__ csr,
                                                 const uint2* __restrict__ hh4,
                                                 const float* __restrict__ w2l,
                                                 const float* __restrict__ b2,
                                                 const float* __restrict__ w2r,
                                                 const int* __restrict__ batch,
                                                 const float* __restrict__ ginv,
                                                 float* __restrict__ out) {
    __shared__ int lcsr[SEGCAP];            // 8 KB
    __shared__ float wlT[CHID * COUT];
    __shared__ float wrT[CHID * COUT];
    __shared__ float bs[COUT];
    __shared__ float mean_s[32 * CHID];
    __shared__ float pool[4 * COUT];
    __shared__ int used[4];
    __shared__ int seg_s, seg_l;
    int tid = threadIdx.x;
    int node0 = blockIdx.x * 32;
    for (int idx = tid; idx < CHID * COUT; idx += 256) {
        int i = idx >> 6, o = idx & 63;
        wlT[idx] = w2l[o * CHID + i];
        wrT[idx] = w2r[o * CHID + i];
    }
    if (tid < COUT) bs[tid] = b2[tid];
    if (tid < 4 * COUT) pool[tid] = 0.f;
    if (tid < 4) used[tid] = 0;
    if (tid == 0) {
        int s = offs[node0];
        int last = node0 + 31;
        int e = offs[last] + ((deg[last] + 7) & ~7);
        seg_s = s;
        seg_l = min(e - s, SEGCAP);        // 40-sigma margin; guard vs corruption
    }
    __syncthreads();
    int segS = seg_s, segL = seg_l;
    const int4* g4 = (const int4*)(csr + segS);
    int4* l4 = (int4*)lcsr;
    for (int i = tid; i < (segL >> 2); i += 256) l4[i] = g4[i];
    __syncthreads();

    int slot = tid >> 3;
    int sub  = (tid >> 2) & 1;
    int c4   = tid & 3;
    int node = node0 + slot;                // grid exact
    int gbase = batch[node0];
    int gid = batch[node];
    int gloc = min(gid - gbase, 3);
    float gw = ginv[gid];
    if ((tid & 7) == 0) used[gloc] = 1;

    int s0 = offs[node] - segS;
    int d  = deg[node];
    int tot = (d + 7) >> 3;
    int itA = (tot + 1) >> 1;
    int myIters = sub ? (tot - itA) : itA;
    const int4* cp4 = (const int4*)(lcsr + s0 + (sub ? (itA << 3) : 0));
    float4 a0 = {0,0,0,0}, a1 = {0,0,0,0}, a2 = {0,0,0,0}, a3 = {0,0,0,0};
    float4 a4 = {0,0,0,0}, a5 = {0,0,0,0}, a6 = {0,0,0,0}, a7 = {0,0,0,0};
    for (int it = 0; it < myIters; it++, cp4 += 2) {
        int4 w0 = cp4[0], w1 = cp4[1];
        a0 += unpack_h4(hh4[(size_t)w0.x * 4 + c4]);
        a1 += unpack_h4(hh4[(size_t)w0.y * 4 + c4]);
        a2 += unpack_h4(hh4[(size_t)w0.z * 4 + c4]);
        a3 += unpack_h4(hh4[(size_t)w0.w * 4 + c4]);
        a4 += unpack_h4(hh4[(size_t)w1.x * 4 + c4]);
        a5 += unpack_h4(hh4[(size_t)w1.y * 4 + c4]);
        a6 += unpack_h4(hh4[(size_t)w1.z * 4 + c4]);
        a7 += unpack_h4(hh4[(size_t)w1.w * 4 + c4]);
    }
    float4 s = ((a0 + a1) + (a2 + a3)) + ((a4 + a5) + (a6 + a7));
    s.x += __shfl_xor(s.x, 4);
    s.y += __shfl_xor(s.y, 4);
    s.z += __shfl_xor(s.z, 4);
    s.w += __shfl_xor(s.w, 4);
    if (sub == 0) {
        float inv = 1.0f / (float)max(d, 1);
        ((float4*)mean_s)[slot * 4 + c4] =
            make_float4(s.x * inv, s.y * inv, s.z * inv, s.w * inv);
    }
    __syncthreads();

    float hv[CHID], m[CHID];
#pragma unroll
    for (int q = 0; q < 4; q++) {
        float4 f = unpack_h4(hh4[(size_t)node * 4 + q]);
        hv[4*q] = f.x; hv[4*q+1] = f.y; hv[4*q+2] = f.z; hv[4*q+3] = f.w;
    }
#pragma unroll
    for (int i = 0; i < CHID; i++) m[i] = mean_s[slot * CHID + i];

    // 8 consecutive outputs per lane; float4 weight reads (broadcast across slots)
    int ob = (tid & 7) * 8;
    float acc[8];
#pragma unroll
    for (int k = 0; k < 8; k++) acc[k] = bs[ob + k];
#pragma unroll
    for (int i = 0; i < CHID; i++) {
        float4 wla = *(const float4*)&wlT[i * COUT + ob];
        float4 wlb = *(const float4*)&wlT[i * COUT + ob + 4];
        float4 wra = *(const float4*)&wrT[i * COUT + ob];
        float4 wrb = *(const float4*)&wrT[i * COUT + ob + 4];
        float mi = m[i], hi = hv[i];
        acc[0] = fmaf(wla.x, mi, acc[0]); acc[1] = fmaf(wla.y, mi, acc[1]);
        acc[2] = fmaf(wla.z, mi, acc[2]); acc[3] = fmaf(wla.w, mi, acc[3]);
        acc[4] = fmaf(wlb.x, mi, acc[4]); acc[5] = fmaf(wlb.y, mi, acc[5]);
        acc[6] = fmaf(wlb.z, mi, acc[6]); acc[7] = fmaf(wlb.w, mi, acc[7]);
        acc[0] = fmaf(wra.x, hi, acc[0]); acc[1] = fmaf(wra.y, hi, acc[1]);
        acc[2] = fmaf(wra.z, hi, acc[2]); acc[3] = fmaf(wra.w, hi, acc[3]);
        acc[4] = fmaf(wrb.x, hi, acc[4]); acc[5] = fmaf(wrb.y, hi, acc[5]);
        acc[6] = fmaf(wrb.z, hi, acc[6]); acc[7] = fmaf(wrb.w, hi, acc[7]);
    }
#pragma unroll
    for (int k = 0; k < 8; k++)
        atomicAdd(&pool[gloc * COUT + ob + k], acc[k] * gw);
    __syncthreads();
    if (tid < 4 * COUT) {
        int row = tid >> 6;
        if (used[row]) atomicAdd(&out[(gbase + row) * COUT + (tid & 63)], pool[tid]);
    }
}

extern "C" void kernel_launch(void* const* d_in, const int* in_sizes, int n_in,
                              void* d_out, int out_size, void* d_ws, size_t ws_size,
                              hipStream_t stream) {
    const float* x    = (const float*)d_in[0];
    const int*   ei   = (const int*)d_in[1];   // [2, E] int32
    const int*   batch= (const int*)d_in[2];
    const float* w1l  = (const float*)d_in[3];
    const float* b1   = (const float*)d_in[4];
    const float* w1r  = (const float*)d_in[5];
    const float* w2l  = (const float*)d_in[6];
    const float* b2   = (const float*)d_in[7];
    const float* w2r  = (const float*)d_in[8];
    float* out = (float*)d_out;

    const int* src = ei;
    const int* dst = ei + NEDGES;

    int*     ws_i = (int*)d_ws;
    float*   ws_f = (float*)d_ws;
    int*     gcnt = ws_i + OFF_GCNT;
    float*   ginv = ws_f + OFF_GINV;
    int*     offs = ws_i + OFF_OFFS;
    int*     deg  = ws_i + OFF_DEG;
    int*     csr  = ws_i + OFF_CSR;
    int*     ebuf = ws_i + OFF_EBUF;
    __half2* xlh2 = (__half2*)(ws_i + OFF_XLH);
    uint2*   xlh4 = (uint2*)(ws_i + OFF_XLH);
    float*   xr   = ws_f + OFF_XR;
    uint2*   hh4  = (uint2*)(ws_i + OFF_HH);

    (void)hipMemsetAsync(gcnt, 0, 512 * sizeof(int), stream);
    (void)hipMemsetAsync(out, 0, NGRAPH * COUT * sizeof(float), stream);

    build_stage1<<<NTB + TBL + 1, 512, 0, stream>>>(src, dst, gcnt, ebuf,
                                                    x, w1l, b1, w1r, xlh2, xr,
                                                    batch, ginv);
    build_agg1  <<<NHALF, 1024, 0, stream>>>(gcnt, ebuf, csr, offs, deg,
                                             xlh4, xr, hh4);
    agg2_pool   <<<AGG_BLOCKS, 256, 0, stream>>>(offs, deg, csr, hh4, w2l, b2, w2r,
                                                 batch, ginv, out);
}

// Round 18
// 208.842 us; speedup vs baseline: 1.0298x; 1.0298x over previous
//
#include <hip/hip_runtime.h>
#include <hip/hip_bf16.h>
#include <hip/hip_fp16.h>

#define NNODES 100000
#define NEDGES 2500000
#define CIN 32
#define CHID 16
#define COUT 64
#define NGRAPH 64

#define NPB 256                 // nodes per binsort bucket
#define NBUCKET 391             // ceil(100000/256)
#define BCAP 7424               // per-bucket raw capacity (mean 6394, ~13 sigma)
#define TILE 8192               // edges per binsort block (R14-proven)
#define NTB 306                 // ceil(2.5M/8192)
#define TBL 196                 // ceil(100000/512) transform blocks
#define NHALF 782               // 2 half-buckets (128 nodes) per bucket
#define BSTRIDE_H 4864          // per-half padded csr stride
#define AGG_BLOCKS 3125         // 100000 / 32 nodes per block (8 lanes/node)

// ---------------- workspace layout (4-byte units) ----------------------------
// gcnt  [0, 512)               int, zeroed (391 used)
// ginv  [1024, 1088)           f32
// offs  [1088, 101088)         int (padded csr start per node)
// deg   [101120, 201120)       int (true in-degree)
// csr   [201216, 4004864)      int, per-half stride BSTRIDE_H, pad = NNODES
// ebuf  [4004864, 6907648)     int packed (src<<8)|dst_local
// xlh   [6907648, 7707712)     f16 (N+1)*16 (row N = zeros)
// xr    [7707712, 9307712)     f32 N*16
// hh    [9307712, 10107720)    f16 (N+1)*16 (row N = zeros)  => 40.4 MB
#define OFF_GCNT  0
#define OFF_GINV  1024
#define OFF_OFFS  1088
#define OFF_DEG   101120
#define OFF_CSR   201216
#define OFF_EBUF  4004864
#define OFF_XLH   6907648
#define OFF_XR    7707712
#define OFF_HH    9307712

__device__ inline float4 unpack_h4(uint2 v) {
    __half2 p0 = *reinterpret_cast<__half2*>(&v.x);
    __half2 p1 = *reinterpret_cast<__half2*>(&v.y);
    float2 f0 = __half22float2(p0), f1 = __half22float2(p1);
    return make_float4(f0.x, f0.y, f1.x, f1.y);
}

__device__ inline uint2 pack_h4(float a, float b, float c, float d) {
    __half2 h0 = __floats2half2_rn(a, b);
    __half2 h1 = __floats2half2_rn(c, d);
    uint2 r;
    r.x = *reinterpret_cast<unsigned int*>(&h0);
    r.y = *reinterpret_cast<unsigned int*>(&h1);
    return r;
}

__device__ inline int lower_bound_i(const int* __restrict__ b, int n, int key) {
    int lo = 0, hi = n;
    while (lo < hi) {
        int m = (lo + hi) >> 1;
        if (b[m] < key) lo = m + 1; else hi = m;
    }
    return lo;
}

// FUSED stage 1: blocks [0,306) binsort | [306,502) transform1 | 502 graph_inv.
__global__ __launch_bounds__(512) void build_stage1(const int* __restrict__ src,
                                                    const int* __restrict__ dst,
                                                    int* __restrict__ gcnt,
                                                    int* __restrict__ ebuf,
                                                    const float* __restrict__ x,
                                                    const float* __restrict__ w1l,
                                                    const float* __restrict__ b1,
                                                    const float* __restrict__ w1r,
                                                    __half2* __restrict__ xlh2,
                                                    float* __restrict__ xr,
                                                    const int* __restrict__ batch,
                                                    float* __restrict__ ginv) {
    __shared__ int hist[NBUCKET];
    __shared__ int binstart[NBUCKET];
    __shared__ int cursor[NBUCKET];
    __shared__ int gbase[NBUCKET];
    __shared__ int tmp[512];
    __shared__ int sbuf[TILE];
    __shared__ float wl[CHID * CIN];
    __shared__ float wr[CHID * CIN];
    __shared__ float bs[CHID];

    int tid = threadIdx.x;

    if (blockIdx.x < NTB) {
        // ================= binsort =================
        int base = blockIdx.x * TILE;
        int cnt = min(NEDGES - base, TILE);
        for (int i = tid; i < NBUCKET; i += 512) hist[i] = 0;
        __syncthreads();
        int v[16], k[16];
#pragma unroll
        for (int j = 0; j < 16; j++) {
            int i = tid + j * 512;
            if (i < cnt) {
                int d = dst[base + i], s = src[base + i];
                k[j] = d >> 8;
                v[j] = (s << 8) | (d & 255);
                atomicAdd(&hist[k[j]], 1);
            }
        }
        __syncthreads();
        int hv = (tid < NBUCKET) ? hist[tid] : 0;
        tmp[tid] = hv;
        __syncthreads();
#pragma unroll
        for (int dd = 1; dd < 512; dd <<= 1) {
            int u = (tid >= dd) ? tmp[tid - dd] : 0;
            __syncthreads();
            tmp[tid] += u;
            __syncthreads();
        }
        if (tid < NBUCKET) {
            int excl = tmp[tid] - hv;
            binstart[tid] = excl;
            cursor[tid] = excl;
            gbase[tid] = (hv > 0) ? atomicAdd(&gcnt[tid], hv) : 0;
        }
        __syncthreads();
#pragma unroll
        for (int j = 0; j < 16; j++) {
            int i = tid + j * 512;
            if (i < cnt) {
                int p = atomicAdd(&cursor[k[j]], 1);
                sbuf[p] = v[j];
            }
        }
        __syncthreads();
        int wave = tid >> 6, lane = tid & 63;
        for (int b = wave; b < NBUCKET; b += 8) {
            int c2 = hist[b];
            if (c2 == 0) continue;
            int g = gbase[b];
            int gs = min(g, BCAP);
            int ncopy = min(g + c2, BCAP) - gs;    // overflow-guarded
            int ls = binstart[b];
            int* dp = ebuf + (size_t)b * BCAP + gs;
            for (int i = lane; i < ncopy; i += 64) dp[i] = sbuf[ls + i];
        }
    } else if (blockIdx.x < NTB + TBL) {
        // ================= transform1 =================
        int bid = blockIdx.x - NTB;
        for (int i = tid; i < CHID * CIN; i += 512) { wl[i] = w1l[i]; wr[i] = w1r[i]; }
        if (tid < CHID) bs[tid] = b1[tid];
        if (bid == 0 && tid < 8)
            xlh2[(size_t)NNODES * 8 + tid] = __floats2half2_rn(0.f, 0.f);  // pad row
        __syncthreads();
        int n = bid * 512 + tid;
        if (n >= NNODES) return;
        float xv[CIN];
        const float4* x4 = (const float4*)(x + (size_t)n * CIN);
#pragma unroll
        for (int q = 0; q < CIN / 4; q++) {
            float4 v = x4[q];
            xv[4*q] = v.x; xv[4*q+1] = v.y; xv[4*q+2] = v.z; xv[4*q+3] = v.w;
        }
        float oL[CHID];
#pragma unroll
        for (int o = 0; o < CHID; o++) {
            float aL = 0.f, aR = bs[o];
#pragma unroll
            for (int i = 0; i < CIN; i++) {
                aL = fmaf(wl[o * CIN + i], xv[i], aL);
                aR = fmaf(wr[o * CIN + i], xv[i], aR);
            }
            oL[o] = aL;
            xr[(size_t)n * CHID + o] = aR;
        }
#pragma unroll
        for (int q = 0; q < CHID / 2; q++)
            xlh2[(size_t)n * 8 + q] = __floats2half2_rn(oL[2*q], oL[2*q+1]);
    } else {
        // ================= graph_inv =================
        if (tid < NGRAPH) {
            int s = lower_bound_i(batch, NNODES, tid);
            int e = lower_bound_i(batch, NNODES, tid + 1);
            ginv[tid] = 1.0f / (float)max(e - s, 1);
        }
    }
}

// FUSED bucket_build + layer-1 aggregation (R14/R16-proven: scalar lcsr reads
// — quad-broadcast ds_read_b32, conflict-free; R17's int4 variant conflicted).
// Block 0 also zeroes `out` (runs strictly before agg2) — replaces a memset.
__global__ __launch_bounds__(1024) void build_agg1(const int* __restrict__ gcnt,
                                                   const int* __restrict__ ebuf,
                                                   int* __restrict__ csr,
                                                   int* __restrict__ offs,
                                                   int* __restrict__ deg,
                                                   const uint2* __restrict__ xlh4,
                                                   const float* __restrict__ xr,
                                                   uint2* __restrict__ hh4,
                                                   float* __restrict__ out) {
    __shared__ int lcsr[BSTRIDE_H];       // 19.5 KB padded LDS csr
    __shared__ int hist[128];
    __shared__ int cur[128];
    __shared__ int offs_s[128];
    __shared__ int deg_s[128];
    __shared__ int tmp[128];
    int b = blockIdx.x, tid = threadIdx.x;
    int b256 = b >> 1, half = b & 1;
    int nodes0 = (b256 << 8) + (half << 7);
    int nloc = min(128, NNODES - nodes0);
    int cnt = min(gcnt[b256], BCAP);
    int hbit = half << 7;
    if (tid < 128) hist[tid] = 0;
    if (b == 0) {
        if (tid < 4) {
            uint2 z; z.x = 0u; z.y = 0u;
            hh4[(size_t)NNODES * 4 + tid] = z;     // zero hh pad row for agg2
        }
        for (int i = tid; i < NGRAPH * COUT; i += 1024) out[i] = 0.f;
    }
    __syncthreads();
    const int* run = ebuf + (size_t)b256 * BCAP;
    for (int i = tid; i < cnt; i += 1024) {
        int dl = run[i] & 255;
        if ((dl & 128) == hbit) atomicAdd(&hist[dl & 127], 1);
    }
    __syncthreads();
    if (tid < 128) tmp[tid] = (hist[tid] + 7) & ~7;
    __syncthreads();
#pragma unroll
    for (int s = 1; s < 128; s <<= 1) {
        int u = (tid < 128 && tid >= s) ? tmp[tid - s] : 0;
        __syncthreads();
        if (tid < 128) tmp[tid] += u;
        __syncthreads();
    }
    if (tid < 128) {
        int d = hist[tid];
        int pc = (d + 7) & ~7;
        int excl = tmp[tid] - pc;
        cur[tid] = excl;
        offs_s[tid] = excl;
        deg_s[tid] = d;
        if (tid < nloc) {
            offs[nodes0 + tid] = b * BSTRIDE_H + excl;
            deg[nodes0 + tid] = d;
        }
    }
    __syncthreads();
    int* bcsr = csr + (size_t)b * BSTRIDE_H;
    for (int i = tid; i < cnt; i += 1024) {
        int v = run[i];
        int dl = v & 255;
        if ((dl & 128) == hbit) {
            int p = atomicAdd(&cur[dl & 127], 1);
            int sid = v >> 8;
            lcsr[p] = sid;
            bcsr[p] = sid;                 // mirror for agg2
        }
    }
    __syncthreads();
    if (tid < 128) {
        int fs = cur[tid];
        int fe = offs_s[tid] + ((deg_s[tid] + 7) & ~7);
        for (int k2 = fs; k2 < fe; k2++) { lcsr[k2] = NNODES; bcsr[k2] = NNODES; }
    }
    __syncthreads();

    // ---- aggregation: 128 slots x 8 lanes (2 half-lists x 4 channel-lanes) --
    int slot = tid >> 3;
    int sub  = (tid >> 2) & 1;
    int c4   = tid & 3;
    int s0 = offs_s[slot];
    int d  = deg_s[slot];
    int tot = (d + 7) >> 3;
    int itA = (tot + 1) >> 1;
    int myIters = sub ? (tot - itA) : itA;
    const int* cp = lcsr + s0 + (sub ? (itA << 3) : 0);
    float4 a0 = {0,0,0,0}, a1 = {0,0,0,0}, a2 = {0,0,0,0}, a3 = {0,0,0,0};
    float4 a4 = {0,0,0,0}, a5 = {0,0,0,0}, a6 = {0,0,0,0}, a7 = {0,0,0,0};
    for (int it = 0; it < myIters; it++, cp += 8) {
        int sA = cp[0], sB = cp[1], sC = cp[2], sD = cp[3];
        int sE = cp[4], sF = cp[5], sG = cp[6], sH = cp[7];
        a0 += unpack_h4(xlh4[(size_t)sA * 4 + c4]);
        a1 += unpack_h4(xlh4[(size_t)sB * 4 + c4]);
        a2 += unpack_h4(xlh4[(size_t)sC * 4 + c4]);
        a3 += unpack_h4(xlh4[(size_t)sD * 4 + c4]);
        a4 += unpack_h4(xlh4[(size_t)sE * 4 + c4]);
        a5 += unpack_h4(xlh4[(size_t)sF * 4 + c4]);
        a6 += unpack_h4(xlh4[(size_t)sG * 4 + c4]);
        a7 += unpack_h4(xlh4[(size_t)sH * 4 + c4]);
    }
    float4 s = ((a0 + a1) + (a2 + a3)) + ((a4 + a5) + (a6 + a7));
    s.x += __shfl_xor(s.x, 4);
    s.y += __shfl_xor(s.y, 4);
    s.z += __shfl_xor(s.z, 4);
    s.w += __shfl_xor(s.w, 4);
    if (sub == 0 && slot < nloc) {
        int node = nodes0 + slot;
        float inv = 1.0f / (float)max(d, 1);
        float4 r = *(const float4*)(xr + (size_t)node * CHID + c4 * 4);
        float h0 = fmaxf(fmaf(s.x, inv, r.x), 0.f);
        float h1 = fmaxf(fmaf(s.y, inv, r.y), 0.f);
        float h2 = fmaxf(fmaf(s.z, inv, r.z), 0.f);
        float h3 = fmaxf(fmaf(s.w, inv, r.w), 0.f);
        hh4[(size_t)node * 4 + c4] = pack_h4(h0, h1, h2, h3);
    }
}

// layer-2 aggregate + output transform + fused graph pooling.
// R16-exact: 3125x256 shape, GLOBAL int4 csr loads (hoisted by compiler,
// conflict-free), 8 consecutive outputs/lane with float4 weight reads.
__global__ __launch_bounds__(256) void agg2_pool(const int* __restrict__ offs,
                                                 const int* __restrict__ deg,
                                                 const int* __restrict__ csr,
                                                 const uint2* __restrict__ hh4,
                                                 const float* __restrict__ w2l,
                                                 const float* __restrict__ b2,
                                                 const float* __restrict__ w2r,
                                                 const int* __restrict__ batch,
                                                 const float* __restrict__ ginv,
                                                 float* __restrict__ out) {
    __shared__ float wlT[CHID * COUT];
    __shared__ float wrT[CHID * COUT];
    __shared__ float bs[COUT];
    __shared__ float mean_s[32 * CHID];
    __shared__ float pool[4 * COUT];
    __shared__ int used[4];
    for (int idx = threadIdx.x; idx < CHID * COUT; idx += 256) {
        int i = idx >> 6, o = idx & 63;
        wlT[idx] = w2l[o * CHID + i];
        wrT[idx] = w2r[o * CHID + i];
    }
    if (threadIdx.x < COUT) bs[threadIdx.x] = b2[threadIdx.x];
    for (int idx = threadIdx.x; idx < 4 * COUT; idx += 256) pool[idx] = 0.f;
    if (threadIdx.x < 4) used[threadIdx.x] = 0;
    __syncthreads();

    int slot = threadIdx.x >> 3;
    int sub  = (threadIdx.x >> 2) & 1;
    int c4   = threadIdx.x & 3;
    int node = blockIdx.x * 32 + slot;      // grid exact
    int gbase = batch[blockIdx.x * 32];
    int gid = batch[node];
    int gloc = min(gid - gbase, 3);
    float gw = ginv[gid];
    if (threadIdx.x % 8 == 0) used[gloc] = 1;

    int s0 = offs[node];
    int d  = deg[node];
    int tot = (d + 7) >> 3;
    int itA = (tot + 1) >> 1;
    int myIters = sub ? (tot - itA) : itA;
    const int4* cp4 = (const int4*)(csr + s0 + (sub ? (itA << 3) : 0));
    float4 a0 = {0,0,0,0}, a1 = {0,0,0,0}, a2 = {0,0,0,0}, a3 = {0,0,0,0};
    float4 a4 = {0,0,0,0}, a5 = {0,0,0,0}, a6 = {0,0,0,0}, a7 = {0,0,0,0};
    for (int it = 0; it < myIters; it++, cp4 += 2) {
        int4 w0 = cp4[0], w1 = cp4[1];
        a0 += unpack_h4(hh4[(size_t)w0.x * 4 + c4]);
        a1 += unpack_h4(hh4[(size_t)w0.y * 4 + c4]);
        a2 += unpack_h4(hh4[(size_t)w0.z * 4 + c4]);
        a3 += unpack_h4(hh4[(size_t)w0.w * 4 + c4]);
        a4 += unpack_h4(hh4[(size_t)w1.x * 4 + c4]);
        a5 += unpack_h4(hh4[(size_t)w1.y * 4 + c4]);
        a6 += unpack_h4(hh4[(size_t)w1.z * 4 + c4]);
        a7 += unpack_h4(hh4[(size_t)w1.w * 4 + c4]);
    }
    float4 s = ((a0 + a1) + (a2 + a3)) + ((a4 + a5) + (a6 + a7));
    s.x += __shfl_xor(s.x, 4);
    s.y += __shfl_xor(s.y, 4);
    s.z += __shfl_xor(s.z, 4);
    s.w += __shfl_xor(s.w, 4);
    if (sub == 0) {
        float inv = 1.0f / (float)max(d, 1);
        ((float4*)mean_s)[slot * 4 + c4] =
            make_float4(s.x * inv, s.y * inv, s.z * inv, s.w * inv);
    }
    __syncthreads();

    float hv[CHID], m[CHID];
#pragma unroll
    for (int q = 0; q < 4; q++) {
        float4 f = unpack_h4(hh4[(size_t)node * 4 + q]);
        hv[4*q] = f.x; hv[4*q+1] = f.y; hv[4*q+2] = f.z; hv[4*q+3] = f.w;
    }
#pragma unroll
    for (int i = 0; i < CHID; i++) m[i] = mean_s[slot * CHID + i];

    // 8 consecutive outputs per lane; float4 weight reads (broadcast across slots)
    int ob = (threadIdx.x & 7) * 8;
    float acc[8];
#pragma unroll
    for (int k = 0; k < 8; k++) acc[k] = bs[ob + k];
#pragma unroll
    for (int i = 0; i < CHID; i++) {
        float4 wla = *(const float4*)&wlT[i * COUT + ob];
        float4 wlb = *(const float4*)&wlT[i * COUT + ob + 4];
        float4 wra = *(const float4*)&wrT[i * COUT + ob];
        float4 wrb = *(const float4*)&wrT[i * COUT + ob + 4];
        float mi = m[i], hi = hv[i];
        acc[0] = fmaf(wla.x, mi, acc[0]); acc[1] = fmaf(wla.y, mi, acc[1]);
        acc[2] = fmaf(wla.z, mi, acc[2]); acc[3] = fmaf(wla.w, mi, acc[3]);
        acc[4] = fmaf(wlb.x, mi, acc[4]); acc[5] = fmaf(wlb.y, mi, acc[5]);
        acc[6] = fmaf(wlb.z, mi, acc[6]); acc[7] = fmaf(wlb.w, mi, acc[7]);
        acc[0] = fmaf(wra.x, hi, acc[0]); acc[1] = fmaf(wra.y, hi, acc[1]);
        acc[2] = fmaf(wra.z, hi, acc[2]); acc[3] = fmaf(wra.w, hi, acc[3]);
        acc[4] = fmaf(wrb.x, hi, acc[4]); acc[5] = fmaf(wrb.y, hi, acc[5]);
        acc[6] = fmaf(wrb.z, hi, acc[6]); acc[7] = fmaf(wrb.w, hi, acc[7]);
    }
#pragma unroll
    for (int k = 0; k < 8; k++)
        atomicAdd(&pool[gloc * COUT + ob + k], acc[k] * gw);
    __syncthreads();
    for (int idx = threadIdx.x; idx < 4 * COUT; idx += 256) {
        int row = idx >> 6;
        if (used[row]) atomicAdd(&out[(gbase + row) * COUT + (idx & 63)], pool[idx]);
    }
}

extern "C" void kernel_launch(void* const* d_in, const int* in_sizes, int n_in,
                              void* d_out, int out_size, void* d_ws, size_t ws_size,
                              hipStream_t stream) {
    const float* x    = (const float*)d_in[0];
    const int*   ei   = (const int*)d_in[1];   // [2, E] int32
    const int*   batch= (const int*)d_in[2];
    const float* w1l  = (const float*)d_in[3];
    const float* b1   = (const float*)d_in[4];
    const float* w1r  = (const float*)d_in[5];
    const float* w2l  = (const float*)d_in[6];
    const float* b2   = (const float*)d_in[7];
    const float* w2r  = (const float*)d_in[8];
    float* out = (float*)d_out;

    const int* src = ei;
    const int* dst = ei + NEDGES;

    int*     ws_i = (int*)d_ws;
    float*   ws_f = (float*)d_ws;
    int*     gcnt = ws_i + OFF_GCNT;
    float*   ginv = ws_f + OFF_GINV;
    int*     offs = ws_i + OFF_OFFS;
    int*     deg  = ws_i + OFF_DEG;
    int*     csr  = ws_i + OFF_CSR;
    int*     ebuf = ws_i + OFF_EBUF;
    __half2* xlh2 = (__half2*)(ws_i + OFF_XLH);
    uint2*   xlh4 = (uint2*)(ws_i + OFF_XLH);
    float*   xr   = ws_f + OFF_XR;
    uint2*   hh4  = (uint2*)(ws_i + OFF_HH);

    (void)hipMemsetAsync(gcnt, 0, 512 * sizeof(int), stream);

    build_stage1<<<NTB + TBL + 1, 512, 0, stream>>>(src, dst, gcnt, ebuf,
                                                    x, w1l, b1, w1r, xlh2, xr,
                                                    batch, ginv);
    build_agg1  <<<NHALF, 1024, 0, stream>>>(gcnt, ebuf, csr, offs, deg,
                                             xlh4, xr, hh4, out);
    agg2_pool   <<<AGG_BLOCKS, 256, 0, stream>>>(offs, deg, csr, hh4, w2l, b2, w2r,
                                                 batch, ginv, out);
}